// Round 11
// baseline (692.275 us; speedup 1.0000x reference)
//
#include <hip/hip_runtime.h>
#include <hip/hip_bf16.h>

typedef float f32x4 __attribute__((ext_vector_type(4)));
typedef __bf16 bf16x8 __attribute__((ext_vector_type(8)));
typedef unsigned short u16x8 __attribute__((ext_vector_type(8)));

#define GN_EPS 1e-5f
#define LN_EPS 1e-5f
#define COS_EPS_F 1e-8f

__device__ __forceinline__ unsigned short f2bf(float f) {
  unsigned int u = __builtin_bit_cast(unsigned int, f);
  u += 0x7fffu + ((u >> 16) & 1u);   // round-to-nearest-even
  return (unsigned short)(u >> 16);
}

// ---------------------------------------------------------------------------
// Coalesced transpose + bf16 cast: x[b][ci][hw] f32 -> xT(+m*stride)[b][hw][ci].
// ---------------------------------------------------------------------------
__global__ void transpose_kernel(const float* __restrict__ x0,
                                 const float* __restrict__ x1,
                                 const float* __restrict__ x2,
                                 unsigned short* __restrict__ xT,
                                 unsigned int strideElems, int mBase) {
  __shared__ float lds[64][129];
  int m = mBase + (blockIdx.x >> 11);
  int bid = blockIdx.x & 2047;          // b*8 + cit*4 + hwt
  const float* x = (m == 0) ? x0 : ((m == 1) ? x1 : x2);
  unsigned short* dst = xT + (unsigned int)(m - mBase) * strideElems;

  int hwt = bid & 3, cit = (bid >> 2) & 1, b = bid >> 3;
  int hw0 = hwt * 64, ci0 = cit * 128;
  int tid = threadIdx.x;

  int hwx = tid & 63, cy0 = tid >> 6;
  const float* xb = x + (b * 256 + ci0) * 256 + hw0;
  #pragma unroll 8
  for (int p = 0; p < 32; ++p) {
    int cy = cy0 + 4 * p;
    lds[hwx][cy] = xb[cy * 256 + hwx];
  }
  __syncthreads();

  int cp = tid & 63, hy0 = tid >> 6;
  unsigned int* outp = (unsigned int*)(dst + (b * 256 + hw0) * 256 + ci0);
  #pragma unroll 4
  for (int p = 0; p < 16; ++p) {
    int hy = hy0 + 4 * p;
    float lo = lds[hy][2 * cp];
    float hi = lds[hy][2 * cp + 1];
    unsigned int w = ((unsigned int)f2bf(hi) << 16) | f2bf(lo);
    outp[hy * 128 + cp] = w;
  }
}

// ---------------------------------------------------------------------------
// Repack conv weights (all 3): W[co][ci][3][3] f32 -> wp[m][co][9][ci] bf16
// ---------------------------------------------------------------------------
__global__ void pack_kernel(const float* __restrict__ w0,
                            const float* __restrict__ w1,
                            const float* __restrict__ w2,
                            unsigned short* __restrict__ wp) {
  int m = blockIdx.y;
  const float* w = (m == 0) ? w0 : ((m == 1) ? w1 : w2);
  int idx = blockIdx.x * 256 + threadIdx.x;   // 0..589823
  int ci = idx & 255;
  int rest = idx >> 8;
  int khw = rest % 9, co = rest / 9;
  wp[m * 589824 + idx] = f2bf(w[(co * 256 + ci) * 9 + khw]);
}

// ---------------------------------------------------------------------------
// Fused Conv3x3 + bias + GroupNorm + ReLU + mean — BARRIER-FREE inner loop.
// Block = 1 image x 128 co (M=256 px, N=128 co), 256 threads, 4 waves
// (2M x 2N), wave tile 128x64, acc[8][4].
// B (weights): NO LDS — read global->VGPR per wave (L2-resident, 1.2 MB/m;
//   mistake #7: don't stage what caches). P/Q prefetch one tap ahead.
// A (image): LDS, [2 bufs][256 px][32 ci], staged ONCE per ci-chunk kc via
//   global_load_lds; all 9 taps read shifted rows (borders -> zbuf cndmask,
//   verified R10); XOR chunk swizzle c^((row>>1)&3) on source+reads (2-way).
// Synchronization: barriers ONLY at kc boundaries (2 per 9 tiles) — within
//   a kc, waves free-run; compiler's fine-grained lgkm/vmcnt schedules.
// ---------------------------------------------------------------------------
__device__ __forceinline__ void gl_lds16(const unsigned short* g, unsigned short* l) {
  __builtin_amdgcn_global_load_lds(
      (const __attribute__((address_space(1))) void*)g,
      (__attribute__((address_space(3))) void*)l, 16, 0, 0);
}

__launch_bounds__(256, 2)
__global__ void conv_gn_pool(const unsigned short* __restrict__ xT,
                             unsigned int xTstride,
                             const unsigned short* __restrict__ wp,
                             const float* __restrict__ cb0, const float* __restrict__ cb1,
                             const float* __restrict__ cb2,
                             const float* __restrict__ gg0, const float* __restrict__ gg1,
                             const float* __restrict__ gg2,
                             const float* __restrict__ gb0, const float* __restrict__ gb1,
                             const float* __restrict__ gb2,
                             float* __restrict__ enc, int mBase, int cpx) {
  __shared__ unsigned short As[2][8192];   // 32 KB: 2 bufs x (256 px x 32 ci)
  __shared__ unsigned short zbuf[32];      // 64 B zero block for borders
  __shared__ float gsum[8], gsq[8], pooled[128];

  int bid = blockIdx.x;
  int wgid = (bid & 7) * cpx + (bid >> 3);  // XCD swizzle (bijective, grid%8==0)
  int mm = mBase + (wgid >> 9);
  int rest = wgid & 511;
  int img = rest >> 1, nt = rest & 1;       // both co-halves of an image adjacent
                                            // -> same XCD -> A L2-shared
  const float* cbias = (mm == 0) ? cb0 : ((mm == 1) ? cb1 : cb2);
  const float* gng   = (mm == 0) ? gg0 : ((mm == 1) ? gg1 : gg2);
  const float* gnb   = (mm == 0) ? gb0 : ((mm == 1) ? gb1 : gb2);

  int tid = threadIdx.x;
  int wid = tid >> 6, lane = tid & 63;
  int wr = wid >> 1, wc = wid & 1;          // 2M x 2N
  int l15 = lane & 15, l4 = lane >> 4;

  if (tid < 8) { gsum[tid] = 0.f; gsq[tid] = 0.f; }
  if (tid < 128) pooled[tid] = 0.f;
  if (tid < 32) zbuf[tid] = 0;

  const unsigned short* xb =
      xT + (unsigned int)(mm - mBase) * xTstride + (unsigned int)img * 65536u;
  const unsigned short* wpB = wp + mm * 589824 + nt * 128 * 2304;

  // ---- A staging sources (4 gl_lds/thread; source pre-swizzled, rule 21) ----
  const unsigned short* aS[4];
  #pragma unroll
  for (int j = 0; j < 4; ++j) {
    int c = j * 256 + tid;
    int r = c >> 2, ch = c & 3;
    aS[j] = xb + r * 256 + ((ch ^ ((r >> 1) & 3)) * 8);
  }

  // ---- B pointers (per-lane, direct global) ----
  const unsigned short* bP[4];
  #pragma unroll
  for (int nf = 0; nf < 4; ++nf) {
    int co = wc * 64 + nf * 16 + l15;
    bP[nf] = wpB + co * 2304 + l4 * 8;
  }

  // ---- A frag row attrs ----
  int p8[8];
  bool hge1[8], hle14[8], wge1[8], wle14[8];
  #pragma unroll
  for (int mf = 0; mf < 8; ++mf) {
    int p = wr * 128 + mf * 16 + l15;
    p8[mf] = p;
    hge1[mf] = (p >> 4) >= 1;  hle14[mf] = (p >> 4) <= 14;
    wge1[mf] = (p & 15) >= 1;  wle14[mf] = (p & 15) <= 14;
  }

  f32x4 acc[8][4];
  #pragma unroll
  for (int i = 0; i < 8; ++i)
    #pragma unroll
    for (int j = 0; j < 4; ++j) acc[i][j] = (f32x4)(0.0f);

  #define LD8(P) __builtin_bit_cast(bf16x8, *(const u16x8*)(P))
  #define STAGE_A(KCN, BUF)                                                    \
    { _Pragma("unroll")                                                        \
      for (int j = 0; j < 4; ++j)                                              \
        gl_lds16(aS[j] + (KCN) * 32, As[BUF] + (j * 256 + tid) * 8); }

  u16x8 Pb[4], Qb[4];
  #define PF(REGS, TAPN)                                                       \
    { _Pragma("unroll")                                                        \
      for (int nf = 0; nf < 4; ++nf)                                           \
        REGS[nf] = *(const u16x8*)(bP[nf] + kco + (TAPN) * 256); }

  #define TAP(DH, DW, CUR, NXT, PFT)                                           \
    {                                                                          \
      if ((PFT) >= 0) PF(NXT, PFT);                                            \
      bf16x8 af[8];                                                            \
      _Pragma("unroll")                                                        \
      for (int mf = 0; mf < 8; ++mf) {                                         \
        int pp = p8[mf] + ((DH) - 1) * 16 + ((DW) - 1);                        \
        bool ok = true;                                                        \
        if ((DH) == 0) ok = ok && hge1[mf];                                    \
        if ((DH) == 2) ok = ok && hle14[mf];                                   \
        if ((DW) == 0) ok = ok && wge1[mf];                                    \
        if ((DW) == 2) ok = ok && wle14[mf];                                   \
        const unsigned short* pa =                                             \
            ok ? AsC + (pp * 32 + ((l4 ^ ((pp >> 1) & 3)) * 8))                \
               : &zbuf[l4 * 8];                                                \
        af[mf] = LD8(pa);                                                      \
      }                                                                        \
      _Pragma("unroll")                                                        \
      for (int mf = 0; mf < 8; ++mf)                                           \
        _Pragma("unroll")                                                      \
        for (int nf = 0; nf < 4; ++nf)                                         \
          acc[mf][nf] = __builtin_amdgcn_mfma_f32_16x16x32_bf16(               \
              af[mf], __builtin_bit_cast(bf16x8, CUR[nf]), acc[mf][nf],        \
              0, 0, 0);                                                        \
    }

  // ---- prologue: A(0) staged, drained, visible ----
  STAGE_A(0, 0);
  asm volatile("s_waitcnt vmcnt(0)" ::: "memory");
  __builtin_amdgcn_s_barrier();

  for (int kc = 0; kc < 8; ++kc) {
    if (kc < 7) STAGE_A(kc + 1, (kc + 1) & 1);   // into buf last read at kc-1
    const unsigned short* AsC = As[kc & 1];
    int kco = kc * 32;
    PF(Pb, 0);
    TAP(0, 0, Pb, Qb, 1)
    TAP(0, 1, Qb, Pb, 2)
    TAP(0, 2, Pb, Qb, 3)
    TAP(1, 0, Qb, Pb, 4)
    TAP(1, 1, Pb, Qb, 5)
    TAP(1, 2, Qb, Pb, 6)
    TAP(2, 0, Pb, Qb, 7)
    TAP(2, 1, Qb, Pb, 8)
    TAP(2, 2, Pb, Qb, -1)
    asm volatile("s_waitcnt vmcnt(0)" ::: "memory");  // A(kc+1) landed
    __builtin_amdgcn_s_barrier();                     // all waves done with buf
  }
  #undef TAP
  #undef PF
  #undef STAGE_A
  #undef LD8

  // ---- epilogue: +bias, group stats (8 groups in this co-half) ----
  float bias[4], ggv[4], gbv[4];
  #pragma unroll
  for (int nf = 0; nf < 4; ++nf) {
    int co = nt * 128 + wc * 64 + nf * 16 + l15;
    bias[nf] = cbias[co]; ggv[nf] = gng[co]; gbv[nf] = gnb[co];
  }
  #pragma unroll
  for (int nf = 0; nf < 4; ++nf) {
    float s1 = 0.f, s2 = 0.f;
    #pragma unroll
    for (int mf = 0; mf < 8; ++mf)
      #pragma unroll
      for (int i = 0; i < 4; ++i) {
        float v = acc[mf][nf][i] + bias[nf];
        acc[mf][nf][i] = v;
        s1 += v; s2 += v * v;
      }
    #pragma unroll
    for (int d = 1; d < 64; d <<= 1) {
      s1 += __shfl_xor(s1, d);
      s2 += __shfl_xor(s2, d);
    }
    if (lane == 0) {
      atomicAdd(&gsum[wc * 4 + nf], s1);
      atomicAdd(&gsq[wc * 4 + nf], s2);
    }
  }
  __syncthreads();
  #pragma unroll
  for (int nf = 0; nf < 4; ++nf) {
    int g = wc * 4 + nf;
    float mean = gsum[g] * (1.f / 4096.f);
    float var = gsq[g] * (1.f / 4096.f) - mean * mean;
    float rs = rsqrtf(var + GN_EPS);
    float p = 0.f;
    #pragma unroll
    for (int mf = 0; mf < 8; ++mf)
      #pragma unroll
      for (int i = 0; i < 4; ++i) {
        float v = (acc[mf][nf][i] - mean) * rs * ggv[nf] + gbv[nf];
        p += fmaxf(v, 0.f);
      }
    p += __shfl_xor(p, 16);
    p += __shfl_xor(p, 32);
    if (lane < 16) atomicAdd(&pooled[wc * 64 + nf * 16 + l15], p);
  }
  __syncthreads();
  if (tid < 128)
    enc[mm * 65536 + img * 256 + nt * 128 + tid] = pooled[tid] * (1.f / 256.f);
}

// ---------------------------------------------------------------------------
// Projector + LN + l2norm + predictor. One block per row (768 rows).
// ---------------------------------------------------------------------------
__global__ void proj_pred(const float* __restrict__ enc,
                          const float* __restrict__ w1, const float* __restrict__ b1,
                          const float* __restrict__ w2, const float* __restrict__ b2,
                          const float* __restrict__ lng, const float* __restrict__ lnb,
                          const float* __restrict__ pw1, const float* __restrict__ pb1,
                          const float* __restrict__ pw2, const float* __restrict__ pb2,
                          float* __restrict__ proj, float* __restrict__ pred,
                          float* __restrict__ znorm) {
  __shared__ float row[256], h1[256], zz[128], p1[128], red[2];
  int r = blockIdx.x, tid = threadIdx.x;
  row[tid] = enc[r * 256 + tid];
  __syncthreads();
  float a = 0.f;
  for (int k = 0; k < 256; ++k) a += row[k] * w1[k * 256 + tid];
  h1[tid] = fmaxf(a + b1[tid], 0.f);
  __syncthreads();
  if (tid < 128) {
    a = 0.f;
    for (int k = 0; k < 256; ++k) a += h1[k] * w2[k * 128 + tid];
    zz[tid] = a + b2[tid];
  }
  __syncthreads();
  if (tid == 0) {
    float m = 0.f;
    for (int k = 0; k < 128; ++k) m += zz[k];
    m *= (1.f / 128.f);
    float v = 0.f;
    for (int k = 0; k < 128; ++k) { float d = zz[k] - m; v += d * d; }
    red[0] = m;
    red[1] = rsqrtf(v * (1.f / 128.f) + LN_EPS);
  }
  __syncthreads();
  float zval = 0.f;
  if (tid < 128) {
    zval = (zz[tid] - red[0]) * red[1] * lng[tid] + lnb[tid];
    proj[r * 128 + tid] = zval;
  }
  __syncthreads();
  if (tid < 128) zz[tid] = zval;
  __syncthreads();
  if (tid == 0) {
    float s = 0.f;
    for (int k = 0; k < 128; ++k) s += zz[k] * zz[k];
    red[0] = 1.f / fmaxf(sqrtf(s), COS_EPS_F);
  }
  __syncthreads();
  if (tid < 128) {
    znorm[r * 128 + tid] = zz[tid] * red[0];
    a = 0.f;
    for (int k = 0; k < 128; ++k) a += zz[k] * pw1[k * 128 + tid];
    p1[tid] = fmaxf(a + pb1[tid], 0.f);
  }
  __syncthreads();
  if (tid < 128) {
    a = 0.f;
    for (int k = 0; k < 128; ++k) a += p1[k] * pw2[k * 128 + tid];
    pred[r * 128 + tid] = a + pb2[tid];
  }
}

// ---------------------------------------------------------------------------
// Loss: block = (pair, k). lse(S[k,:]) - S[k,k] per row; partials to ws.
// ---------------------------------------------------------------------------
__global__ void loss_kernel(const float* __restrict__ zn, float* __restrict__ part) {
  __shared__ float zi[128], sv[256], rbuf[256];
  int blk = blockIdx.x;
  int p = blk >> 8, k = blk & 255;
  int i = (p == 2) ? 1 : 0;
  int j = (p == 0) ? 1 : 2;
  int tid = threadIdx.x;
  if (tid < 128) zi[tid] = zn[(i * 256 + k) * 128 + tid];
  __syncthreads();
  const float4* zj = (const float4*)&zn[(j * 256 + tid) * 128];
  float s = 0.f;
  #pragma unroll 8
  for (int d = 0; d < 32; ++d) {
    float4 aq = *(const float4*)&zi[d * 4];
    float4 bq = zj[d];
    s += aq.x * bq.x + aq.y * bq.y + aq.z * bq.z + aq.w * bq.w;
  }
  s *= 10.0f;
  sv[tid] = s;
  rbuf[tid] = s;
  __syncthreads();
  for (int d = 128; d > 0; d >>= 1) {
    if (tid < d) rbuf[tid] = fmaxf(rbuf[tid], rbuf[tid + d]);
    __syncthreads();
  }
  float m = rbuf[0];
  __syncthreads();
  rbuf[tid] = expf(s - m);
  __syncthreads();
  for (int d = 128; d > 0; d >>= 1) {
    if (tid < d) rbuf[tid] += rbuf[tid + d];
    __syncthreads();
  }
  if (tid == 0) part[blk] = m + logf(rbuf[0]) - sv[k];
}

__global__ void finalize_loss(const float* __restrict__ part, float* __restrict__ out) {
  __shared__ float red[256];
  int tid = threadIdx.x;
  float s = 0.f;
  for (int idx = tid; idx < 768; idx += 256) s += part[idx];
  red[tid] = s;
  __syncthreads();
  for (int d = 128; d > 0; d >>= 1) {
    if (tid < d) red[tid] += red[tid + d];
    __syncthreads();
  }
  if (tid == 0) out[0] = red[0] * (1.f / 768.f);
}

// ---------------------------------------------------------------------------
extern "C" void kernel_launch(void* const* d_in, const int* in_sizes, int n_in,
                              void* d_out, int out_size, void* d_ws, size_t ws_size,
                              hipStream_t stream) {
  const float* x[3]  = {(const float*)d_in[0], (const float*)d_in[1], (const float*)d_in[2]};
  const float* cw[3] = {(const float*)d_in[3], (const float*)d_in[7], (const float*)d_in[11]};
  const float* cb[3] = {(const float*)d_in[4], (const float*)d_in[8], (const float*)d_in[12]};
  const float* gg[3] = {(const float*)d_in[5], (const float*)d_in[9], (const float*)d_in[13]};
  const float* gb[3] = {(const float*)d_in[6], (const float*)d_in[10], (const float*)d_in[14]};
  const float* p_w1 = (const float*)d_in[15];
  const float* p_b1 = (const float*)d_in[16];
  const float* p_w2 = (const float*)d_in[17];
  const float* p_b2 = (const float*)d_in[18];
  const float* ln_g = (const float*)d_in[19];
  const float* ln_b = (const float*)d_in[20];
  const float* q_w1 = (const float*)d_in[21];
  const float* q_b1 = (const float*)d_in[22];
  const float* q_w2 = (const float*)d_in[23];
  const float* q_b2 = (const float*)d_in[24];

  float* out = (float*)d_out;
  char* ws = (char*)d_ws;

  const size_t XT_ONE = 33554432;
  bool merged = ws_size >= (3 * XT_ONE + 3538944 + 393216 + 3072);

  size_t xt_total = merged ? 3 * XT_ONE : XT_ONE;
  unsigned short* xT  = (unsigned short*)ws;
  unsigned short* wpk = (unsigned short*)(ws + xt_total);
  float* znorm = (float*)(ws + xt_total + 3538944);
  float* part  = (float*)(ws + xt_total + 3538944 + 393216);

  float* enc  = out;              // [3][256][256]
  float* proj = out + 196608;     // [3][256][128]
  float* pred = out + 294912;     // [3][256][128]
  float* lossp = out + 393216;    // scalar

  pack_kernel<<<dim3(2304, 3), dim3(256), 0, stream>>>(cw[0], cw[1], cw[2], wpk);

  if (merged) {
    transpose_kernel<<<dim3(6144), dim3(256), 0, stream>>>(x[0], x[1], x[2], xT, 16777216u, 0);
    conv_gn_pool<<<dim3(1536), dim3(256), 0, stream>>>(
        xT, 16777216u, wpk, cb[0], cb[1], cb[2], gg[0], gg[1], gg[2],
        gb[0], gb[1], gb[2], enc, 0, 192);
  } else {
    for (int m = 0; m < 3; ++m) {
      transpose_kernel<<<dim3(2048), dim3(256), 0, stream>>>(x[0], x[1], x[2], xT, 0u, m);
      conv_gn_pool<<<dim3(512), dim3(256), 0, stream>>>(
          xT, 0u, wpk, cb[0], cb[1], cb[2], gg[0], gg[1], gg[2],
          gb[0], gb[1], gb[2], enc, m, 64);
    }
  }
  proj_pred<<<dim3(768), dim3(256), 0, stream>>>(enc, p_w1, p_b1, p_w2, p_b2, ln_g, ln_b,
                                                 q_w1, q_b1, q_w2, q_b2, proj, pred, znorm);
  loss_kernel<<<dim3(768), dim3(256), 0, stream>>>(znorm, part);
  finalize_loss<<<dim3(1), dim3(256), 0, stream>>>(part, lossp);
}

// Round 12
// 299.753 us; speedup vs baseline: 2.3095x; 2.3095x over previous
//
#include <hip/hip_runtime.h>
#include <hip/hip_bf16.h>

typedef float f32x4 __attribute__((ext_vector_type(4)));
typedef __bf16 bf16x8 __attribute__((ext_vector_type(8)));
typedef unsigned short u16x8 __attribute__((ext_vector_type(8)));

#define GN_EPS 1e-5f
#define LN_EPS 1e-5f
#define COS_EPS_F 1e-8f

__device__ __forceinline__ unsigned short f2bf(float f) {
  unsigned int u = __builtin_bit_cast(unsigned int, f);
  u += 0x7fffu + ((u >> 16) & 1u);   // round-to-nearest-even
  return (unsigned short)(u >> 16);
}

// ---------------------------------------------------------------------------
// Coalesced transpose + bf16 cast: x[b][ci][hw] f32 -> xT(+m*stride)[b][hw][ci].
// ---------------------------------------------------------------------------
__global__ void transpose_kernel(const float* __restrict__ x0,
                                 const float* __restrict__ x1,
                                 const float* __restrict__ x2,
                                 unsigned short* __restrict__ xT,
                                 unsigned int strideElems, int mBase) {
  __shared__ float lds[64][129];
  int m = mBase + (blockIdx.x >> 11);
  int bid = blockIdx.x & 2047;          // b*8 + cit*4 + hwt
  const float* x = (m == 0) ? x0 : ((m == 1) ? x1 : x2);
  unsigned short* dst = xT + (unsigned int)(m - mBase) * strideElems;

  int hwt = bid & 3, cit = (bid >> 2) & 1, b = bid >> 3;
  int hw0 = hwt * 64, ci0 = cit * 128;
  int tid = threadIdx.x;

  int hwx = tid & 63, cy0 = tid >> 6;
  const float* xb = x + (b * 256 + ci0) * 256 + hw0;
  #pragma unroll 8
  for (int p = 0; p < 32; ++p) {
    int cy = cy0 + 4 * p;
    lds[hwx][cy] = xb[cy * 256 + hwx];
  }
  __syncthreads();

  int cp = tid & 63, hy0 = tid >> 6;
  unsigned int* outp = (unsigned int*)(dst + (b * 256 + hw0) * 256 + ci0);
  #pragma unroll 4
  for (int p = 0; p < 16; ++p) {
    int hy = hy0 + 4 * p;
    float lo = lds[hy][2 * cp];
    float hi = lds[hy][2 * cp + 1];
    unsigned int w = ((unsigned int)f2bf(hi) << 16) | f2bf(lo);
    outp[hy * 128 + cp] = w;
  }
}

// ---------------------------------------------------------------------------
// Repack conv weights (all 3): W[co][ci][3][3] f32 -> wp[m][co][9][ci] bf16
// ---------------------------------------------------------------------------
__global__ void pack_kernel(const float* __restrict__ w0,
                            const float* __restrict__ w1,
                            const float* __restrict__ w2,
                            unsigned short* __restrict__ wp,
                            unsigned short* __restrict__ zerobuf) {
  int m = blockIdx.y;
  const float* w = (m == 0) ? w0 : ((m == 1) ? w1 : w2);
  int idx = blockIdx.x * 256 + threadIdx.x;   // 0..589823
  if (m == 0 && blockIdx.x == 0) zerobuf[threadIdx.x] = 0;
  int ci = idx & 255;
  int rest = idx >> 8;
  int khw = rest % 9, co = rest / 9;
  wp[m * 589824 + idx] = f2bf(w[(co * 256 + ci) * 9 + khw]);
}

// ---------------------------------------------------------------------------
// Fused Conv3x3 (implicit GEMM, bf16 MFMA) + bias + GroupNorm(16) + ReLU +
// spatial mean.  One block = one image: 256 spatial x 256 co, K=2304.
// K order: ci-chunk outer, tap inner (L2-friendly).  BK=32, 4 LDS buffers.
// FULL REGISTER DOUBLE-BUFFER: all 12 frags of tile t+1 are ds_read during
// tile t into the alternate P/Q register set; explicit counted
// s_waitcnt lgkmcnt(12) before the MFMAs waits only for tile t's frags and
// leaves t+1's 12 reads in flight -> LDS pipe services them UNDER the
// 1242-cyc MFMA phase (the serialization all prior variants shared).
// Per tile: STAGE(t+2) -> vmcnt(4) [t+1 landed] -> s_barrier ->
//           READF(t+1 -> NXT regs) -> lgkmcnt(12) -> sched_barrier ->
//           32 MFMA on CUR regs.  One barrier/tile.
// Liveness: reads of buf[(t+1)&3] at tile t; stage(t+2) overwrites
// buf[(t-2)&3] last read at t-3, drained by t-2's lgkmcnt, >=2 barriers ago.
// Swizzle: chunk c of row r at slot c ^ ((r>>1)&3) (2-way = free).
// ---------------------------------------------------------------------------
__device__ __forceinline__ void gl_lds16(const unsigned short* g, unsigned short* l) {
  __builtin_amdgcn_global_load_lds(
      (const __attribute__((address_space(1))) void*)g,
      (__attribute__((address_space(3))) void*)l, 16, 0, 0);
}

__launch_bounds__(512, 2)
__global__ void conv_gn_pool(const unsigned short* __restrict__ xT,
                             unsigned int xTstride,
                             const unsigned short* __restrict__ wp,
                             const unsigned short* __restrict__ zb,
                             const float* __restrict__ cb0, const float* __restrict__ cb1,
                             const float* __restrict__ cb2,
                             const float* __restrict__ gg0, const float* __restrict__ gg1,
                             const float* __restrict__ gg2,
                             const float* __restrict__ gb0, const float* __restrict__ gb1,
                             const float* __restrict__ gb2,
                             float* __restrict__ enc, int mBase) {
  __shared__ unsigned short Ab[4][8192];   // 64 KB
  __shared__ unsigned short Bb[4][8192];   // 64 KB
  __shared__ float gsum[16], gsq[16], pooled[256];

  int mm = mBase + (blockIdx.x >> 8);
  int bb = blockIdx.x & 255;
  int b = (bb & 7) * 32 + (bb >> 3);       // XCD swizzle (bijective)
  const float* cbias = (mm == 0) ? cb0 : ((mm == 1) ? cb1 : cb2);
  const float* gng   = (mm == 0) ? gg0 : ((mm == 1) ? gg1 : gg2);
  const float* gnb   = (mm == 0) ? gb0 : ((mm == 1) ? gb1 : gb2);

  int tid = threadIdx.x;
  int wid = tid >> 6, lane = tid & 63;
  int wr = wid >> 2, wc = wid & 3;         // wave grid 2(M) x 4(N); tile 128x64
  int l15 = lane & 15, l4 = lane >> 4;

  if (tid < 16) { gsum[tid] = 0.f; gsq[tid] = 0.f; }
  if (tid < 256) pooled[tid] = 0.f;

  // ---- staging geometry: 2048 16B-chunks per tile, 4 per thread ----
  int s0 = tid, s1 = 512 + tid;
  int r0 = s0 >> 2, c0 = s0 & 3;
  int r1 = s1 >> 2, c1 = s1 & 3;
  int cs0 = (c0 ^ ((r0 >> 1) & 3)) * 8;    // source pre-swizzle (rule 21)
  int cs1 = (c1 ^ ((r1 >> 1) & 3)) * 8;
  int rh0 = r0 >> 4, rw0 = r0 & 15;
  int rh1 = r1 >> 4, rw1 = r1 & 15;

  const unsigned short* xb = xT + (unsigned int)(mm - mBase) * xTstride + b * 65536;
  const unsigned short* wpm = wp + mm * 589824;
  const unsigned short* bB0 = wpm + r0 * 2304 + cs0;
  const unsigned short* bB1 = wpm + r1 * 2304 + cs1;

  // ---- LDS read offsets (ushort units) ----
  int kch = (l4 ^ ((l15 >> 1) & 3)) * 8;
  int base_af = (wr * 128 + l15) * 32 + kch;
  int base_bf = (wc * 64 + l15) * 32 + kch;

  f32x4 acc[8][4];
  #pragma unroll
  for (int i = 0; i < 8; ++i)
    #pragma unroll
    for (int j = 0; j < 4; ++j) acc[i][j] = (f32x4)(0.0f);

  // staging tile counter (tap fastest: tile = kc*9 + khw)
  int kc3 = 0, kh3 = 0, kw3 = 0;

  #define STAGE(SBUF)                                                          \
    {                                                                          \
      int ci0_ = kc3 * 32;                                                     \
      unsigned short* dstA = &Ab[(SBUF)][0];                                   \
      int h0_ = rh0 + kh3 - 1, w0_ = rw0 + kw3 - 1;                            \
      const unsigned short* sA0 = ((unsigned)h0_ < 16u && (unsigned)w0_ < 16u) \
          ? xb + ((h0_ * 16 + w0_) * 256 + ci0_ + cs0) : zb;                   \
      gl_lds16(sA0, dstA + s0 * 8);                                            \
      int h1_ = rh1 + kh3 - 1, w1_ = rw1 + kw3 - 1;                            \
      const unsigned short* sA1 = ((unsigned)h1_ < 16u && (unsigned)w1_ < 16u) \
          ? xb + ((h1_ * 16 + w1_) * 256 + ci0_ + cs1) : zb;                   \
      gl_lds16(sA1, dstA + s1 * 8);                                            \
      int offB = (kh3 * 3 + kw3) * 256 + ci0_;                                 \
      unsigned short* dstB = &Bb[(SBUF)][0];                                   \
      gl_lds16(bB0 + offB, dstB + s0 * 8);                                     \
      gl_lds16(bB1 + offB, dstB + s1 * 8);                                     \
      kw3 = kw3 + 1; int cw_ = (kw3 == 3); kw3 = cw_ ? 0 : kw3; kh3 += cw_;    \
      int ch_ = (kh3 == 3); kh3 = ch_ ? 0 : kh3; kc3 += ch_;                   \
    }

  #define LD8(P) __builtin_bit_cast(bf16x8, *(const u16x8*)(P))

  bf16x8 afP[8], bfrP[4], afQ[8], bfrQ[4];

  #define READF(AF, BF, BUFI)                                                  \
    {                                                                          \
      const unsigned short* Ap_ = &Ab[(BUFI)][0];                              \
      const unsigned short* Bp_ = &Bb[(BUFI)][0];                              \
      _Pragma("unroll")                                                        \
      for (int j = 0; j < 8; ++j) AF[j] = LD8(&Ap_[base_af + j * 512]);        \
      _Pragma("unroll")                                                        \
      for (int n = 0; n < 4; ++n) BF[n] = LD8(&Bp_[base_bf + n * 512]);        \
    }

  #define MM(AF, BF)                                                           \
    {                                                                          \
      __builtin_amdgcn_s_setprio(1);                                           \
      _Pragma("unroll")                                                        \
      for (int j = 0; j < 8; ++j)                                              \
        _Pragma("unroll")                                                      \
        for (int n = 0; n < 4; ++n)                                            \
          acc[j][n] = __builtin_amdgcn_mfma_f32_16x16x32_bf16(                 \
              AF[j], BF[n], acc[j][n], 0, 0, 0);                               \
      __builtin_amdgcn_s_setprio(0);                                           \
    }

  // ---- prologue: stage 0,1; read tile-0 frags -> P ----
  STAGE(0); STAGE(1);
  asm volatile("s_waitcnt vmcnt(4)" ::: "memory");   // tile 0 landed
  __builtin_amdgcn_s_barrier();
  READF(afP, bfrP, 0);                               // 12 lgkm outstanding

  // ---- main: t = 0..69, unroll 2 (P even / Q odd) ----
  for (int t2 = 0; t2 < 35; ++t2) {
    {
      int t = 2 * t2;
      STAGE((t + 2) & 3);
      asm volatile("s_waitcnt vmcnt(4)" ::: "memory");   // t+1 landed
      __builtin_amdgcn_s_barrier();
      READF(afQ, bfrQ, (t + 1) & 3);
      asm volatile("s_waitcnt lgkmcnt(12)" ::: "memory"); // t's frags done
      __builtin_amdgcn_sched_barrier(0);
      MM(afP, bfrP);
    }
    {
      int t = 2 * t2 + 1;
      STAGE((t + 2) & 3);
      asm volatile("s_waitcnt vmcnt(4)" ::: "memory");
      __builtin_amdgcn_s_barrier();
      READF(afP, bfrP, (t + 1) & 3);
      asm volatile("s_waitcnt lgkmcnt(12)" ::: "memory");
      __builtin_amdgcn_sched_barrier(0);
      MM(afQ, bfrQ);
    }
  }
  // ---- t = 70 (even, CUR=P): no stage ----
  asm volatile("s_waitcnt vmcnt(0)" ::: "memory");   // tile 71 landed
  __builtin_amdgcn_s_barrier();
  READF(afQ, bfrQ, 3);                               // 71 & 3
  asm volatile("s_waitcnt lgkmcnt(12)" ::: "memory");
  __builtin_amdgcn_sched_barrier(0);
  MM(afP, bfrP);
  // ---- t = 71 (odd, CUR=Q): no stage, no reads ----
  asm volatile("s_waitcnt lgkmcnt(0)" ::: "memory");
  __builtin_amdgcn_sched_barrier(0);
  MM(afQ, bfrQ);
  #undef MM
  #undef READF
  #undef STAGE
  #undef LD8

  __syncthreads();

  // ---- epilogue: +bias, group stats (16 groups fully inside this block) ----
  float bias[4], ggv[4], gbv[4];
  #pragma unroll
  for (int nf = 0; nf < 4; ++nf) {
    int co = wc * 64 + nf * 16 + l15;
    bias[nf] = cbias[co]; ggv[nf] = gng[co]; gbv[nf] = gnb[co];
  }
  #pragma unroll
  for (int nf = 0; nf < 4; ++nf) {
    float s1 = 0.f, s2 = 0.f;
    #pragma unroll
    for (int mf = 0; mf < 8; ++mf)
      #pragma unroll
      for (int i = 0; i < 4; ++i) {
        float v = acc[mf][nf][i] + bias[nf];
        acc[mf][nf][i] = v;
        s1 += v; s2 += v * v;
      }
    #pragma unroll
    for (int d = 1; d < 64; d <<= 1) {
      s1 += __shfl_xor(s1, d);
      s2 += __shfl_xor(s2, d);
    }
    if (lane == 0) {
      atomicAdd(&gsum[wc * 4 + nf], s1);
      atomicAdd(&gsq[wc * 4 + nf], s2);
    }
  }
  __syncthreads();
  #pragma unroll
  for (int nf = 0; nf < 4; ++nf) {
    int g = wc * 4 + nf;
    float mean = gsum[g] * (1.f / 4096.f);
    float var = gsq[g] * (1.f / 4096.f) - mean * mean;
    float rs = rsqrtf(var + GN_EPS);
    float p = 0.f;
    #pragma unroll
    for (int mf = 0; mf < 8; ++mf)
      #pragma unroll
      for (int i = 0; i < 4; ++i) {
        float v = (acc[mf][nf][i] - mean) * rs * ggv[nf] + gbv[nf];
        p += fmaxf(v, 0.f);
      }
    p += __shfl_xor(p, 16);
    p += __shfl_xor(p, 32);
    if (lane < 16) atomicAdd(&pooled[wc * 64 + nf * 16 + l15], p);
  }
  __syncthreads();
  if (tid < 256)
    enc[mm * 65536 + b * 256 + tid] = pooled[tid] * (1.f / 256.f);
}

// ---------------------------------------------------------------------------
// Projector + LN + l2norm + predictor. One block per row (768 rows).
// Serial tid==0 sections replaced with tree reductions.
// ---------------------------------------------------------------------------
__global__ void proj_pred(const float* __restrict__ enc,
                          const float* __restrict__ w1, const float* __restrict__ b1,
                          const float* __restrict__ w2, const float* __restrict__ b2,
                          const float* __restrict__ lng, const float* __restrict__ lnb,
                          const float* __restrict__ pw1, const float* __restrict__ pb1,
                          const float* __restrict__ pw2, const float* __restrict__ pb2,
                          float* __restrict__ proj, float* __restrict__ pred,
                          float* __restrict__ znorm) {
  __shared__ float row[256], h1[256], zz[128], p1[128], rbuf[128], red[2];
  int r = blockIdx.x, tid = threadIdx.x;
  row[tid] = enc[r * 256 + tid];
  __syncthreads();
  float a = 0.f;
  for (int k = 0; k < 256; ++k) a += row[k] * w1[k * 256 + tid];
  h1[tid] = fmaxf(a + b1[tid], 0.f);
  __syncthreads();
  if (tid < 128) {
    a = 0.f;
    for (int k = 0; k < 256; ++k) a += h1[k] * w2[k * 128 + tid];
    zz[tid] = a + b2[tid];
  }
  __syncthreads();
  // mean (tree)
  if (tid < 128) rbuf[tid] = zz[tid];
  __syncthreads();
  for (int d = 64; d > 0; d >>= 1) {
    if (tid < d) rbuf[tid] += rbuf[tid + d];
    __syncthreads();
  }
  float mean = rbuf[0] * (1.f / 128.f);
  __syncthreads();
  // var (tree)
  if (tid < 128) { float dv = zz[tid] - mean; rbuf[tid] = dv * dv; }
  __syncthreads();
  for (int d = 64; d > 0; d >>= 1) {
    if (tid < d) rbuf[tid] += rbuf[tid + d];
    __syncthreads();
  }
  float rstd = rsqrtf(rbuf[0] * (1.f / 128.f) + LN_EPS);
  __syncthreads();
  float zval = 0.f;
  if (tid < 128) {
    zval = (zz[tid] - mean) * rstd * lng[tid] + lnb[tid];
    proj[r * 128 + tid] = zval;
    rbuf[tid] = zval * zval;
  }
  __syncthreads();
  if (tid < 128) zz[tid] = zval;
  for (int d = 64; d > 0; d >>= 1) {
    __syncthreads();
    if (tid < d) rbuf[tid] += rbuf[tid + d];
  }
  __syncthreads();
  float rn = 1.f / fmaxf(sqrtf(rbuf[0]), COS_EPS_F);
  __syncthreads();
  if (tid < 128) {
    znorm[r * 128 + tid] = zz[tid] * rn;
    a = 0.f;
    for (int k = 0; k < 128; ++k) a += zz[k] * pw1[k * 128 + tid];
    p1[tid] = fmaxf(a + pb1[tid], 0.f);
  }
  __syncthreads();
  if (tid < 128) {
    a = 0.f;
    for (int k = 0; k < 128; ++k) a += p1[k] * pw2[k * 128 + tid];
    pred[r * 128 + tid] = a + pb2[tid];
  }
}

// ---------------------------------------------------------------------------
// Loss: block = (pair, k). lse(S[k,:]) - S[k,k] per row; partials to ws.
// ---------------------------------------------------------------------------
__global__ void loss_kernel(const float* __restrict__ zn, float* __restrict__ part) {
  __shared__ float zi[128], sv[256], rbuf[256];
  int blk = blockIdx.x;
  int p = blk >> 8, k = blk & 255;
  int i = (p == 2) ? 1 : 0;
  int j = (p == 0) ? 1 : 2;
  int tid = threadIdx.x;
  if (tid < 128) zi[tid] = zn[(i * 256 + k) * 128 + tid];
  __syncthreads();
  const float4* zj = (const float4*)&zn[(j * 256 + tid) * 128];
  float s = 0.f;
  #pragma unroll 8
  for (int d = 0; d < 32; ++d) {
    float4 aq = *(const float4*)&zi[d * 4];
    float4 bq = zj[d];
    s += aq.x * bq.x + aq.y * bq.y + aq.z * bq.z + aq.w * bq.w;
  }
  s *= 10.0f;
  sv[tid] = s;
  rbuf[tid] = s;
  __syncthreads();
  for (int d = 128; d > 0; d >>= 1) {
    if (tid < d) rbuf[tid] = fmaxf(rbuf[tid], rbuf[tid + d]);
    __syncthreads();
  }
  float m = rbuf[0];
  __syncthreads();
  rbuf[tid] = expf(s - m);
  __syncthreads();
  for (int d = 128; d > 0; d >>= 1) {
    if (tid < d) rbuf[tid] += rbuf[tid + d];
    __syncthreads();
  }
  if (tid == 0) part[blk] = m + logf(rbuf[0]) - sv[k];
}

__global__ void finalize_loss(const float* __restrict__ part, float* __restrict__ out) {
  __shared__ float red[256];
  int tid = threadIdx.x;
  float s = 0.f;
  for (int idx = tid; idx < 768; idx += 256) s += part[idx];
  red[tid] = s;
  __syncthreads();
  for (int d = 128; d > 0; d >>= 1) {
    if (tid < d) red[tid] += red[tid + d];
    __syncthreads();
  }
  if (tid == 0) out[0] = red[0] * (1.f / 768.f);
}

// ---------------------------------------------------------------------------
extern "C" void kernel_launch(void* const* d_in, const int* in_sizes, int n_in,
                              void* d_out, int out_size, void* d_ws, size_t ws_size,
                              hipStream_t stream) {
  const float* x[3]  = {(const float*)d_in[0], (const float*)d_in[1], (const float*)d_in[2]};
  const float* cw[3] = {(const float*)d_in[3], (const float*)d_in[7], (const float*)d_in[11]};
  const float* cb[3] = {(const float*)d_in[4], (const float*)d_in[8], (const float*)d_in[12]};
  const float* gg[3] = {(const float*)d_in[5], (const float*)d_in[9], (const float*)d_in[13]};
  const float* gb[3] = {(const float*)d_in[6], (const float*)d_in[10], (const float*)d_in[14]};
  const float* p_w1 = (const float*)d_in[15];
  const float* p_b1 = (const float*)d_in[16];
  const float* p_w2 = (const float*)d_in[17];
  const float* p_b2 = (const float*)d_in[18];
  const float* ln_g = (const float*)d_in[19];
  const float* ln_b = (const float*)d_in[20];
  const float* q_w1 = (const float*)d_in[21];
  const float* q_b1 = (const float*)d_in[22];
  const float* q_w2 = (const float*)d_in[23];
  const float* q_b2 = (const float*)d_in[24];

  float* out = (float*)d_out;
  char* ws = (char*)d_ws;

  const size_t XT_ONE = 33554432;
  bool merged = ws_size >= (3 * XT_ONE + 3538944 + 393216 + 3072 + 512);

  size_t xt_total = merged ? 3 * XT_ONE : XT_ONE;
  unsigned short* xT  = (unsigned short*)ws;
  unsigned short* wpk = (unsigned short*)(ws + xt_total);
  float* znorm = (float*)(ws + xt_total + 3538944);
  float* part  = (float*)(ws + xt_total + 3538944 + 393216);
  unsigned short* zb = (unsigned short*)(ws + xt_total + 3538944 + 393216 + 3072);

  float* enc  = out;              // [3][256][256]
  float* proj = out + 196608;     // [3][256][128]
  float* pred = out + 294912;     // [3][256][128]
  float* lossp = out + 393216;    // scalar

  pack_kernel<<<dim3(2304, 3), dim3(256), 0, stream>>>(cw[0], cw[1], cw[2], wpk, zb);

  if (merged) {
    transpose_kernel<<<dim3(6144), dim3(256), 0, stream>>>(x[0], x[1], x[2], xT, 16777216u, 0);
    conv_gn_pool<<<dim3(768), dim3(512), 0, stream>>>(
        xT, 16777216u, wpk, zb, cb[0], cb[1], cb[2], gg[0], gg[1], gg[2],
        gb[0], gb[1], gb[2], enc, 0);
  } else {
    for (int m = 0; m < 3; ++m) {
      transpose_kernel<<<dim3(2048), dim3(256), 0, stream>>>(x[0], x[1], x[2], xT, 0u, m);
      conv_gn_pool<<<dim3(256), dim3(512), 0, stream>>>(
          xT, 0u, wpk, zb, cb[0], cb[1], cb[2], gg[0], gg[1], gg[2],
          gb[0], gb[1], gb[2], enc, m);
    }
  }
  proj_pred<<<dim3(768), dim3(256), 0, stream>>>(enc, p_w1, p_b1, p_w2, p_b2, ln_g, ln_b,
                                                 q_w1, q_b1, q_w2, q_b2, proj, pred, znorm);
  loss_kernel<<<dim3(768), dim3(256), 0, stream>>>(znorm, part);
  finalize_loss<<<dim3(1), dim3(256), 0, stream>>>(part, lossp);
}